// Round 12
// baseline (4798.316 us; speedup 1.0000x reference)
//
#include <hip/hip_runtime.h>
#include <math.h>

#define HH 96
#define WW 96
#define NWIN 65          // window size
#define NZ 160           // noise row stride
#define L33 33           // half-spectrum range
#define PAD 36           // padded column stride (floats / float2s)
#define NT1 256          // rowdft block
#define NT2 320          // fftma2 block (5 waves; 297 main tasks)

// ---------------- kernel 1: shared sliding row-DFTs ----------------
// rd[px][r][l]: px-major so each fftma2 block reads contiguous spans.
__global__ __launch_bounds__(NT1)
void rowdft_kernel(const float* __restrict__ noise, float2* __restrict__ rd)
{
    __shared__ float row[NZ];
    __shared__ float2 tw[NWIN];
    const int tid = threadIdx.x;
    const int r = blockIdx.x;
    if (tid < NWIN) {
        double a = 6.283185307179586 * (double)tid / 65.0;
        tw[tid] = make_float2((float)cos(a), (float)sin(a));
    }
    if (tid < NZ) row[tid] = noise[r * NZ + tid];
    __syncthreads();

    for (int t = tid; t < 96 * 9; t += NT1) {
        const int px = t / 9;
        const int g = t - 9 * px;
        const int l0 = 4 * g;
        float c0[4], c1[4], s0[4], s1[4], tc2[4], aC[4], aS[4];
        #pragma unroll
        for (int j = 0; j < 4; j++) {
            float2 w = tw[l0 + j];
            c0[j] = 1.f; s0[j] = 0.f;
            c1[j] = w.x; s1[j] = w.y;
            tc2[j] = 2.f * w.x;
            aC[j] = 0.f; aS[j] = 0.f;
        }
        for (int wx = 0; wx < NWIN; ++wx) {
            float v = row[px + wx];
            #pragma unroll
            for (int j = 0; j < 4; j++) {
                aC[j] = fmaf(v, c0[j], aC[j]);
                aS[j] = fmaf(v, s0[j], aS[j]);
                float cn = fmaf(tc2[j], c1[j], -c0[j]);   // Chebyshev step
                float sn = fmaf(tc2[j], s1[j], -s0[j]);
                c0[j] = c1[j]; c1[j] = cn;
                s0[j] = s1[j]; s1[j] = sn;
            }
        }
        #pragma unroll
        for (int j = 0; j < 4; j++) {
            int l = l0 + j;
            if (l < L33) rd[(px * NZ + r) * L33 + l] = make_float2(aC[j], aS[j]);
        }
    }
}

// ---------------- kernel 2: per-pixel spectral pipeline ----------------
// One k-pair per thread (33*9=297 tasks) to keep VGPR<=128 (4 waves/SIMD),
// plus y-fold of the Wf col-DFT: precomputed sum/diff arrays Fp/Fm halve the
// main loop to y=1..32.
__global__ __launch_bounds__(NT2)
void fftma2_kernel(const float* __restrict__ angle,
                   const float2* __restrict__ rd,
                   float* __restrict__ out)
{
    __shared__ float2 tw[NWIN];                       // setup/epilogue only
    __shared__ alignas(16) float  RbT[NWIN][PAD];     // R transposed [y][x], x 0..32
    __shared__ alignas(16) float  Tc[L33][PAD];       // TR real part  [x][l]
    __shared__ alignas(16) float  Ts[L33][PAD];       // TR sin part   [x][l]
    __shared__ alignas(16) float2 Fp[L33][PAD];       // y-fold (wc+, ws-) ; row 0 = (wc0, ws0)
    __shared__ alignas(16) float2 Fm[L33][PAD];       // y-fold (wc-, ws+)
    __shared__ float red[5][4];

    const int tid = threadIdx.x;
    const int p  = blockIdx.x;
    const int py = p / WW;
    const int px = p - py * WW;

    if (tid < NWIN) {
        double a = 6.283185307179586 * (double)tid / 65.0;
        tw[tid] = make_float2((float)cos(a), (float)sin(a));
    }

    const float th = angle[p];
    const float cth = cosf(th), sth = sinf(th);

    // ---- R build (x=0..32; centro-symmetry gives the rest) ----
    for (int e = tid; e < NWIN * PAD; e += NT2) {
        int y = e / PAD, x = e - PAD * y;
        float v = 0.f;
        if (x < L33) {
            float X = (float)x;
            float Y = (float)(y <= 32 ? y : y - 65);
            float u =  X * cth + Y * sth;
            float w = -X * sth + Y * cth;
            float q = fmaf(u * (1.f / 225.f), u, w * (1.f / 9.f) * w);
            v = expf(-sqrtf(q));
        }
        RbT[y][x] = v;
    }
    // ---- fold-stage rowdft from global: Fp/Fm (y=1..32), row 0 raw ----
    {
        const float2* src = rd + (px * NZ + py) * L33;
        for (int e = tid; e < L33 * PAD; e += NT2) {
            int y = e / PAD, l = e - PAD * y;
            float2 fp = make_float2(0.f, 0.f);
            float2 fm = make_float2(0.f, 0.f);
            if (l < L33) {
                float2 a = src[y * L33 + l];
                if (y == 0) {
                    fp = a;                       // (wc0, ws0)
                } else {
                    float2 b = src[(NWIN - y) * L33 + l];
                    fp = make_float2(a.x + b.x, a.y - b.y);   // (wc+, ws-)
                    fm = make_float2(a.x - b.x, a.y + b.y);   // (wc-, ws+)
                }
            }
            Fp[y][l] = fp; Fm[y][l] = fm;
        }
    }
    __syncthreads();

    // ---- stage 3: TR[x][l] = sum_y RbT[y][x]*(cos,sin)(l*y), cheb twiddles ----
    for (int t = tid; t < 9 * PAD; t += NT2) {
        int xg = t / PAD, l = t - PAD * xg;
        int x0 = 4 * xg;
        float aC[4] = {0,0,0,0}, aS[4] = {0,0,0,0};
        float2 wl = tw[l];
        float cm = 1.f, sm = 0.f;
        float cc = wl.x, ss = wl.y;
        float t2 = 2.f * wl.x;
        for (int y = 0; y < NWIN; ++y) {
            const float4 rv = *(const float4*)&RbT[y][x0];
            aC[0] = fmaf(rv.x, cm, aC[0]); aS[0] = fmaf(rv.x, sm, aS[0]);
            aC[1] = fmaf(rv.y, cm, aC[1]); aS[1] = fmaf(rv.y, sm, aS[1]);
            aC[2] = fmaf(rv.z, cm, aC[2]); aS[2] = fmaf(rv.z, sm, aS[2]);
            aC[3] = fmaf(rv.w, cm, aC[3]); aS[3] = fmaf(rv.w, sm, aS[3]);
            float cn = fmaf(t2, cc, -cm);
            float sn = fmaf(t2, ss, -sm);
            cm = cc; sm = ss; cc = cn; ss = sn;
        }
        #pragma unroll
        for (int j = 0; j < 4; j++) {
            int x = x0 + j;
            if (x < L33) { Tc[x][l] = aC[j]; Ts[x][l] = aS[j]; }
        }
    }
    __syncthreads();

    // ---- per-task (one k-pair, l-quad) ----
    float accA = 0.f, accP = 0.f, accC = 0.f, accV = 0.f;
    if (tid < 33 * 9) {
        const int kp = tid / 9;            // 0..32
        const int lg = tid - 9 * kp;
        const int l0 = 4 * lg;

        const float2 wk = tw[kp];
        const float t2k = 2.f * wk.x;

        // ---- Rf fold: P = sum Tc*cos(kx), Q = sum Ts*sin(kx), x=1..32 ----
        const float4 tc0 = *(const float4*)&Tc[0][l0];
        float P[4] = {0,0,0,0}, Q[4] = {0,0,0,0};
        {
            float cm = 1.f, sm = 0.f, cc = wk.x, ss = wk.y;
            for (int x = 1; x < L33; ++x) {
                const float4 c4 = *(const float4*)&Tc[x][l0];
                const float4 s4 = *(const float4*)&Ts[x][l0];
                float cw = cc, sw = ss;
                P[0] = fmaf(c4.x, cw, P[0]); Q[0] = fmaf(s4.x, sw, Q[0]);
                P[1] = fmaf(c4.y, cw, P[1]); Q[1] = fmaf(s4.y, sw, Q[1]);
                P[2] = fmaf(c4.z, cw, P[2]); Q[2] = fmaf(s4.z, sw, Q[2]);
                P[3] = fmaf(c4.w, cw, P[3]); Q[3] = fmaf(s4.w, sw, Q[3]);
                float cn = fmaf(t2k, cw, -cm);
                float sn = fmaf(t2k, sw, -sm);
                cm = cw; sm = sw; cc = cn; ss = sn;
            }
        }
        float rfm_[4], rfp_[4];            // rho for k=kp and k=65-kp
        #pragma unroll
        for (int j = 0; j < 4; j++) {
            float t0 = (j == 0) ? tc0.x : (j == 1) ? tc0.y : (j == 2) ? tc0.z : tc0.w;
            rfm_[j] = fmaf(2.f, P[j] - Q[j], t0);
            rfp_[j] = fmaf(2.f, P[j] + Q[j], t0);
        }

        // ---- Wf col-DFT with y-fold: y=1..32 only ----
        // A=sum wc+*cos, B=sum ws-*sin, C=sum wc-*sin, D=sum ws+*cos
        const float4 f0a = *(const float4*)&Fp[0][l0];       // (wc0,ws0, wc1,ws1)
        const float4 f0b = *(const float4*)&Fp[0][l0 + 2];
        float A[4] = {f0a.x, f0a.z, f0b.x, f0b.z};
        float D[4] = {f0a.y, f0a.w, f0b.y, f0b.w};
        float B[4] = {0,0,0,0}, C[4] = {0,0,0,0};
        {
            float cm = 1.f, sm = 0.f, cc = wk.x, ss = wk.y;
            for (int y = 1; y < L33; ++y) {
                const float4 p01 = *(const float4*)&Fp[y][l0];      // (wc+0,ws-0,wc+1,ws-1)
                const float4 p23 = *(const float4*)&Fp[y][l0 + 2];
                const float4 m01 = *(const float4*)&Fm[y][l0];      // (wc-0,ws+0,wc-1,ws+1)
                const float4 m23 = *(const float4*)&Fm[y][l0 + 2];
                float cw = cc, sw = ss;
                A[0] = fmaf(p01.x, cw, A[0]); B[0] = fmaf(p01.y, sw, B[0]);
                C[0] = fmaf(m01.x, sw, C[0]); D[0] = fmaf(m01.y, cw, D[0]);
                A[1] = fmaf(p01.z, cw, A[1]); B[1] = fmaf(p01.w, sw, B[1]);
                C[1] = fmaf(m01.z, sw, C[1]); D[1] = fmaf(m01.w, cw, D[1]);
                A[2] = fmaf(p23.x, cw, A[2]); B[2] = fmaf(p23.y, sw, B[2]);
                C[2] = fmaf(m23.x, sw, C[2]); D[2] = fmaf(m23.y, cw, D[2]);
                A[3] = fmaf(p23.z, cw, A[3]); B[3] = fmaf(p23.w, sw, B[3]);
                C[3] = fmaf(m23.z, sw, C[3]); D[3] = fmaf(m23.w, cw, D[3]);
                float cn = fmaf(t2k, cw, -cm);
                float sn = fmaf(t2k, sw, -sm);
                cm = cw; sm = sw; cc = cn; ss = sn;
            }
        }

        // ---- epilogue: k=kp (e=0) and k=65-kp (e=1); csqrt + accumulate ----
        #pragma unroll
        for (int e = 0; e < 2; e++) {
            if (e == 1 && kp == 0) continue;
            const int kk = e ? (NWIN - kp) : kp;
            #pragma unroll
            for (int j = 0; j < 4; j++) {
                const int l = l0 + j;
                if (l > 32) continue;
                if (l == 0 && kk > 32) continue;   // mirror of (65-kk,0)
                float wr  = e ? (A[j] + B[j]) : (A[j] - B[j]);
                float wi  = e ? (C[j] - D[j]) : (-(C[j] + D[j]));
                float rho = e ? rfp_[j] : rfm_[j];
                int kl = kk + l; if (kl >= NWIN) kl -= NWIN;
                float2 tkl = tw[kl];
                float zr = fmaf(rho, tkl.x, 1e-8f);
                float zi = rho * tkl.y;
                float rr = sqrtf(zr * zr + zi * zi);
                float Gr = sqrtf(fmaxf(0.5f * (rr + zr), 0.f));
                float Gm = sqrtf(fmaxf(0.5f * (rr - zr), 0.f));
                float Gi = (zi < 0.f) ? -Gm : Gm;   // principal csqrt
                float Fr = wr * Gr - wi * Gi;
                float Fi = wr * Gi + wi * Gr;
                if (kk == 0 && l == 0) {
                    accA += Fr * Fr + Fi * Fi;
                    accP += Fr * Fr - Fi * Fi;
                    accC += Fr;
                    accV += Fr;
                } else {
                    float Gi2 = (zi == 0.f) ? Gi : -Gi;   // branch-cut mirror
                    float Fr2 = wr * Gr + wi * Gi2;
                    float Fi2 = wr * Gi2 - wi * Gr;
                    accA += Fr * Fr + Fi * Fi + Fr2 * Fr2 + Fi2 * Fi2;
                    accP += 2.f * (Fr * Fr2 - Fi * Fi2);
                    int m32 = (32 * (kk + l)) % NWIN;
                    float2 t32 = tw[m32];
                    accC += Fr * t32.x - Fi * t32.y + Fr2 * t32.x + Fi2 * t32.y;
                }
            }
        }
    }

    // ---- block reduction (5 waves) ----
    #pragma unroll
    for (int off = 32; off > 0; off >>= 1) {
        accA += __shfl_down(accA, off);
        accP += __shfl_down(accP, off);
        accC += __shfl_down(accC, off);
        accV += __shfl_down(accV, off);
    }
    int wv = tid >> 6, ln = tid & 63;
    if (ln == 0) { red[wv][0] = accA; red[wv][1] = accP; red[wv][2] = accC; red[wv][3] = accV; }
    __syncthreads();
    if (tid == 0) {
        float Asum = 0.f, Psum = 0.f, Csum = 0.f, Vsum = 0.f;
        #pragma unroll
        for (int w = 0; w < 5; w++) {
            Asum += red[w][0]; Psum += red[w][1];
            Csum += red[w][2]; Vsum += red[w][3];
        }
        const float Ntot = 4225.f;
        float mean = Vsum / Ntot;
        float E2   = (Psum + Asum) * (0.5f / Ntot);
        float cen  = Csum / Ntot;
        float var  = (E2 - Ntot * mean * mean) / (Ntot - 1.f);
        float sd   = sqrtf(fmaxf(var, 0.f));
        out[p] = (cen - mean) / (sd + 1e-6f);
    }
}

extern "C" void kernel_launch(void* const* d_in, const int* in_sizes, int n_in,
                              void* d_out, int out_size, void* d_ws, size_t ws_size,
                              hipStream_t stream)
{
    (void)in_sizes; (void)n_in; (void)out_size; (void)ws_size;
    const float* angle = (const float*)d_in[0];
    const float* noise = (const float*)d_in[1];
    float* outp = (float*)d_out;
    float2* rd = (float2*)d_ws;    // 96*160*33 float2 = 4.06 MB, [px][r][l]

    rowdft_kernel<<<dim3(NZ), dim3(NT1), 0, stream>>>(noise, rd);
    fftma2_kernel<<<dim3(HH * WW), dim3(NT2), 0, stream>>>(angle, rd, outp);
}